// Round 4
// baseline (700.987 us; speedup 1.0000x reference)
//
#include <hip/hip_runtime.h>
#include <hip/hip_bf16.h>

typedef short bf16x8 __attribute__((ext_vector_type(8)));
typedef float f32x4 __attribute__((ext_vector_type(4)));
typedef float f32x16 __attribute__((ext_vector_type(16)));

#define NH 12
#define SEQ 1792
#define DMODEL 1536
#define HD 128

static __device__ __forceinline__ void gload16(const void* g, void* l) {
  __builtin_amdgcn_global_load_lds((const __attribute__((address_space(1))) void*)g,
                                   (__attribute__((address_space(3))) void*)l, 16, 0, 0);
}

static __device__ __forceinline__ short f2bf(float x) {
  __hip_bfloat16 h = __float2bfloat16(x);
  return *reinterpret_cast<short*>(&h);
}

static __device__ __forceinline__ unsigned pack2(float lo, float hi) {
  unsigned a = (unsigned)(unsigned short)f2bf(lo);
  unsigned b = (unsigned)(unsigned short)f2bf(hi);
  return a | (b << 16);
}

// ---------- fp32 -> bf16 cast, x4 vectorized ----------
__global__ __launch_bounds__(256) void cast_kernel(const float* __restrict__ src,
                                                   __hip_bfloat16* __restrict__ dst, int n4) {
  int i = blockIdx.x * 256 + threadIdx.x;
  if (i >= n4) return;
  float4 v = reinterpret_cast<const float4*>(src)[i];
  short4 r;
  r.x = f2bf(v.x); r.y = f2bf(v.y); r.z = f2bf(v.z); r.w = f2bf(v.w);
  reinterpret_cast<short4*>(dst)[i] = r;
}

// ---------- 128x128 bf16 GEMM, B^T layout (C = A @ B^T), m97 structure ----------
template<int MODE>
__global__ __launch_bounds__(256) void gemm_bt(
    const __hip_bfloat16* __restrict__ A, const __hip_bfloat16* __restrict__ B, int K,
    const float* __restrict__ bq, const float* __restrict__ bk, const float* __restrict__ bv,
    __hip_bfloat16* __restrict__ qbuf, __hip_bfloat16* __restrict__ kbuf,
    __hip_bfloat16* __restrict__ vt,
    const float* __restrict__ bo, float* __restrict__ outp)
{
  __shared__ __hip_bfloat16 Abuf[2][128 * 32];
  __shared__ __hip_bfloat16 Bbuf[2][128 * 32];
  const int tid = threadIdx.x;
  const int l = tid & 63, w = tid >> 6;
  const int lr = l & 15, lg = l >> 4;
  const int wr = w >> 1, wc = w & 1;
  const int m0 = blockIdx.y * 128, n0 = blockIdx.x * 128;
  const int nK = K >> 5;

  f32x4 acc[4][4] = {};

  auto stage = [&](int buf, int kk) {
#pragma unroll
    for (int q2 = 0; q2 < 2; ++q2) {
      int flat = q2 * 256 + tid;
      int row = flat >> 2;
      int kb16 = (flat & 3) * 16;
      const __hip_bfloat16* ga = A + (size_t)(m0 + row) * K + kk + (kb16 >> 1);
      gload16(ga, &Abuf[buf][(q2 * 256 + w * 64) * 8]);
      const __hip_bfloat16* gb = B + (size_t)(n0 + row) * K + kk + (kb16 >> 1);
      gload16(gb, &Bbuf[buf][(q2 * 256 + w * 64) * 8]);
    }
  };

  stage(0, 0);
  for (int kt = 0; kt < nK; ++kt) {
    __syncthreads();
    if (kt + 1 < nK) stage((kt + 1) & 1, (kt + 1) * 32);
    const __hip_bfloat16* Ab = Abuf[kt & 1];
    const __hip_bfloat16* Bb = Bbuf[kt & 1];
    bf16x8 af[4], bfr[4];
#pragma unroll
    for (int fi = 0; fi < 4; ++fi)
      af[fi] = *reinterpret_cast<const bf16x8*>(&Ab[(wr * 64 + fi * 16 + lr) * 32 + lg * 8]);
#pragma unroll
    for (int fj = 0; fj < 4; ++fj)
      bfr[fj] = *reinterpret_cast<const bf16x8*>(&Bb[(wc * 64 + fj * 16 + lr) * 32 + lg * 8]);
#pragma unroll
    for (int fi = 0; fi < 4; ++fi)
#pragma unroll
      for (int fj = 0; fj < 4; ++fj)
        acc[fi][fj] = __builtin_amdgcn_mfma_f32_16x16x32_bf16(af[fi], bfr[fj], acc[fi][fj], 0, 0, 0);
  }

  if (MODE == 0) {
#pragma unroll
    for (int fj = 0; fj < 4; ++fj) {
      int ncol = n0 + wc * 64 + fj * 16 + lr;
      int which = ncol / DMODEL;
      int cc = ncol - which * DMODEL;
      int hh = cc >> 7, dd = cc & 127;
      float bias = (which == 0 ? bq : which == 1 ? bk : bv)[cc];
#pragma unroll
      for (int fi = 0; fi < 4; ++fi)
#pragma unroll
        for (int r = 0; r < 4; ++r) {
          int rowg = m0 + wr * 64 + fi * 16 + lg * 4 + r;
          int bbb = rowg / SEQ;
          int sr = rowg - bbb * SEQ;
          __hip_bfloat16 hv = __float2bfloat16(acc[fi][fj][r] + bias);
          if (which == 0)
            qbuf[(((size_t)(bbb * NH + hh)) * SEQ + sr) * HD + dd] = hv;
          else if (which == 1)
            kbuf[(((size_t)(bbb * NH + hh)) * SEQ + sr) * HD + dd] = hv;
          else
            vt[(((size_t)(bbb * NH + hh)) * HD + dd) * SEQ + sr] = hv;
        }
    }
  } else {
#pragma unroll
    for (int fj = 0; fj < 4; ++fj) {
      int ncol = n0 + wc * 64 + fj * 16 + lr;
      float bias = bo[ncol];
#pragma unroll
      for (int fi = 0; fi < 4; ++fi)
#pragma unroll
        for (int r = 0; r < 4; ++r) {
          int rowg = m0 + wr * 64 + fi * 16 + lg * 4 + r;
          outp[(size_t)rowg * DMODEL + ncol] = acc[fi][fj][r] + bias;
        }
    }
  }
}

// ---------- RMSNorm (full-D) + 3D-grid RoPE, in-place on q,k ----------
// q additionally pre-scaled by 1/sqrt(HD) so attention skips the scale.
__global__ __launch_bounds__(256) void rmsrope_kernel(
    __hip_bfloat16* __restrict__ qb, __hip_bfloat16* __restrict__ kb,
    const float* __restrict__ gq, const float* __restrict__ gk,
    const float* __restrict__ fc, const float* __restrict__ fs,
    const int* __restrict__ gsz, const int* __restrict__ nmod)
{
  const int bs = blockIdx.x;
  const int b = bs / SEQ, s = bs - b * SEQ;
  const int t = threadIdx.x;
  const int f = gsz[0], h = gsz[1], wd = gsz[2];
  const int mm = nmod[0];
  const int seq_per = f * h * wd;
  int total_len = seq_per * mm; if (total_len > SEQ) total_len = SEQ;
  const bool dorope = s < total_len;
  int fi = 0, hi2 = 0, wi = 0;
  if (dorope) {
    int p = s % seq_per;
    fi = p / (h * wd);
    int rem = p - fi * (h * wd);
    hi2 = rem / wd;
    wi = rem - hi2 * wd;
  }
  float qv[3][2], kv[3][2];
  float sq = 0.f, sk = 0.f;
#pragma unroll
  for (int r = 0; r < 3; ++r) {
    int pi = t + r * 256;
    int head = pi >> 6;
    int dd = (pi & 63) * 2;
    size_t addr = (((size_t)(b * NH + head)) * SEQ + s) * HD + dd;
    __hip_bfloat162 q2 = *reinterpret_cast<const __hip_bfloat162*>(&qb[addr]);
    __hip_bfloat162 k2 = *reinterpret_cast<const __hip_bfloat162*>(&kb[addr]);
    qv[r][0] = __bfloat162float(q2.x); qv[r][1] = __bfloat162float(q2.y);
    kv[r][0] = __bfloat162float(k2.x); kv[r][1] = __bfloat162float(k2.y);
    sq += qv[r][0] * qv[r][0] + qv[r][1] * qv[r][1];
    sk += kv[r][0] * kv[r][0] + kv[r][1] * kv[r][1];
  }
#pragma unroll
  for (int off = 1; off < 64; off <<= 1) {
    sq += __shfl_xor(sq, off);
    sk += __shfl_xor(sk, off);
  }
  __shared__ float red[2][4];
  if ((t & 63) == 0) { red[0][t >> 6] = sq; red[1][t >> 6] = sk; }
  __syncthreads();
  float tq = red[0][0] + red[0][1] + red[0][2] + red[0][3];
  float tk = red[1][0] + red[1][1] + red[1][2] + red[1][3];
  float rq = rsqrtf(tq * (1.0f / DMODEL) + 1e-6f);
  float rk = rsqrtf(tk * (1.0f / DMODEL) + 1e-6f);
  const float scale = 0.08838834764831845f; // 1/sqrt(128), folded into q
#pragma unroll
  for (int r = 0; r < 3; ++r) {
    int pi = t + r * 256;
    int head = pi >> 6;
    int dd = (pi & 63) * 2;
    int col = pi * 2;
    size_t addr = (((size_t)(b * NH + head)) * SEQ + s) * HD + dd;
    float q0 = qv[r][0] * rq * gq[col], q1 = qv[r][1] * rq * gq[col + 1];
    float k0 = kv[r][0] * rk * gk[col], k1 = kv[r][1] * rk * gk[col + 1];
    if (dorope) {
      int j = pi & 63;
      int row = (j < 22) ? fi : (j < 43) ? hi2 : wi;
      float co = fc[row * 64 + j], si = fs[row * 64 + j];
      float a;
      a = q0 * co - q1 * si; q1 = q0 * si + q1 * co; q0 = a;
      a = k0 * co - k1 * si; k1 = k0 * si + k1 * co; k0 = a;
    }
    q0 *= scale; q1 *= scale;
    __hip_bfloat162 oq, ok;
    oq.x = __float2bfloat16(q0); oq.y = __float2bfloat16(q1);
    ok.x = __float2bfloat16(k0); ok.y = __float2bfloat16(k1);
    *reinterpret_cast<__hip_bfloat162*>(&qb[addr]) = oq;
    *reinterpret_cast<__hip_bfloat162*>(&kb[addr]) = ok;
  }
}

// ---------- flash attention v4: 4 waves x QBLK=32 (128 q-rows/block), NO LDS ----------
// K and V both read directly from global (L1/L2-resident tiles, shared across
// waves); swapped QK^T (lane owns one q-row), in-register softmax, defer-max,
// setprio around MFMA clusters (T5), bijective XCD swizzle (672 = 8 x 84).
__global__ __launch_bounds__(256, 4) void attn_kernel(
    const __hip_bfloat16* __restrict__ qb, const __hip_bfloat16* __restrict__ kbuf,
    const __hip_bfloat16* __restrict__ vt, const int* __restrict__ seq_lens,
    __hip_bfloat16* __restrict__ ob)
{
  // nwg = 672 = 8 * 84: xcd-contiguous remap (6 whole heads per XCD)
  const int orig = blockIdx.x;
  const int wg = (orig & 7) * 84 + (orig >> 3);
  const int bh = wg / 14, qt = wg % 14;
  const int bbb = bh / NH, hh = bh - bbb * NH;
  const int tid = threadIdx.x;
  const int w = tid >> 6, l = tid & 63;
  const int lq = l & 31, h = l >> 5;
  const int sl = seq_lens[bbb];
  const __hip_bfloat16* Q = qb + (size_t)bh * SEQ * HD;
  const __hip_bfloat16* Kp = kbuf + (size_t)bh * SEQ * HD;
  const __hip_bfloat16* Vp = vt + (size_t)bh * HD * SEQ;   // [128][1792]
  const int q0 = qt * 128 + w * 32;

  // Q fragments (B-operand of swapped QK^T): lane holds Q[q0+lq][kc*16 + h*8 + j]
  bf16x8 qf[8];
#pragma unroll
  for (int kc = 0; kc < 8; ++kc)
    qf[kc] = *reinterpret_cast<const bf16x8*>(
        &Q[(size_t)(q0 + lq) * HD + kc * 16 + h * 8]);

  f32x16 oacc[4] = {};                          // O[q_off][d0*32+lq]
  float m = -3e38f, ll = 0.f;                   // per-lane q-row softmax state

  const int nkt = (sl + 63) >> 6;

  for (int kt = 0; kt < nkt; ++kt) {
    const int k0 = kt * 64;

    // swapped QK^T: S^T[k][q], K frags straight from global, 16 mfma_32x32x16
    f32x16 sa[2] = {};
    __builtin_amdgcn_s_setprio(1);
#pragma unroll
    for (int cb = 0; cb < 2; ++cb) {
      const __hip_bfloat16* Krow = Kp + (size_t)(k0 + cb * 32 + lq) * HD + h * 8;
#pragma unroll
      for (int kc = 0; kc < 8; ++kc) {
        bf16x8 kf = *reinterpret_cast<const bf16x8*>(Krow + kc * 16);
        sa[cb] = __builtin_amdgcn_mfma_f32_32x32x16_bf16(kf, qf[kc], sa[cb], 0, 0, 0);
      }
    }
    __builtin_amdgcn_s_setprio(0);

    // mask tail (rare): k of sa[cb][r] = k0 + cb*32 + (r&3) + 8*(r>>2) + 4*h
    if (k0 + 64 > sl) {
#pragma unroll
      for (int cb = 0; cb < 2; ++cb)
#pragma unroll
        for (int r = 0; r < 16; ++r) {
          int kg = k0 + cb * 32 + (r & 3) + 8 * (r >> 2) + 4 * h;
          if (kg >= sl) sa[cb][r] = -3e38f;
        }
    }

    // in-register online softmax: lane owns q-row (lq), halves split across h
    float mx = -3e38f;
#pragma unroll
    for (int cb = 0; cb < 2; ++cb)
#pragma unroll
      for (int r = 0; r < 16; ++r) mx = fmaxf(mx, sa[cb][r]);
    mx = fmaxf(mx, __shfl_xor(mx, 32));

    if (__any(mx - m > 8.f)) {                  // defer-max (T13)
      float mn = fmaxf(m, mx);
      float alpha = __expf(m - mn);
      m = mn;
      ll *= alpha;
#pragma unroll
      for (int r = 0; r < 16; ++r) {
        float ar = __shfl(alpha, (r & 3) + 8 * (r >> 2) + 4 * h);
#pragma unroll
        for (int d0 = 0; d0 < 4; ++d0) oacc[d0][r] *= ar;
      }
    }

    float rs = 0.f;
#pragma unroll
    for (int cb = 0; cb < 2; ++cb)
#pragma unroll
      for (int r = 0; r < 16; ++r) {
        float e = __expf(sa[cb][r] - m);
        sa[cb][r] = e;
        rs += e;
      }
    rs += __shfl_xor(rs, 32);
    ll += rs;

    // P -> bf16 A-frags (pack + shfl_xor(32) exchange) and PV
#pragma unroll
    for (int c = 0; c < 4; ++c) {
      const int cb = c >> 1, r0 = 8 * (c & 1);
      unsigned A01 = pack2(sa[cb][r0],     sa[cb][r0 + 1]);
      unsigned A23 = pack2(sa[cb][r0 + 2], sa[cb][r0 + 3]);
      unsigned B01 = pack2(sa[cb][r0 + 4], sa[cb][r0 + 5]);
      unsigned B23 = pack2(sa[cb][r0 + 6], sa[cb][r0 + 7]);
      unsigned s1 = __shfl_xor(h ? A01 : B01, 32);
      unsigned s2 = __shfl_xor(h ? A23 : B23, 32);
      int4 wv;
      wv.x = (int)(h ? s1 : A01);
      wv.y = (int)(h ? s2 : A23);
      wv.z = (int)(h ? B01 : s1);
      wv.w = (int)(h ? B23 : s2);
      bf16x8 pa = *reinterpret_cast<bf16x8*>(&wv);
      __builtin_amdgcn_s_setprio(1);
#pragma unroll
      for (int d0 = 0; d0 < 4; ++d0) {
        bf16x8 vv = *reinterpret_cast<const bf16x8*>(
            &Vp[(size_t)(d0 * 32 + lq) * SEQ + k0 + c * 16 + h * 8]);
        oacc[d0] = __builtin_amdgcn_mfma_f32_32x32x16_bf16(pa, vv, oacc[d0], 0, 0, 0);
      }
      __builtin_amdgcn_s_setprio(0);
    }
  }

  // epilogue: normalize by per-q-row sum, write O
  float invl = 1.0f / ll;
#pragma unroll
  for (int r = 0; r < 16; ++r) {
    int qoff = (r & 3) + 8 * (r >> 2) + 4 * h;
    float ir = __shfl(invl, qoff);
    int qrow = q0 + qoff;
#pragma unroll
    for (int d0 = 0; d0 < 4; ++d0)
      ob[((size_t)bbb * SEQ + qrow) * DMODEL + hh * HD + d0 * 32 + lq] =
          __float2bfloat16(oacc[d0][r] * ir);
  }
}

// ---------- launch ----------
extern "C" void kernel_launch(void* const* d_in, const int* in_sizes, int n_in,
                              void* d_out, int out_size, void* d_ws, size_t ws_size,
                              hipStream_t stream) {
  const float* x   = (const float*)d_in[0];
  const int* seq_lens   = (const int*)d_in[1];
  const int* grid_sizes = (const int*)d_in[2];
  const float* fc  = (const float*)d_in[3];
  const float* fs  = (const float*)d_in[4];
  const float* Wq  = (const float*)d_in[5];
  const float* bq  = (const float*)d_in[6];
  const float* Wk  = (const float*)d_in[7];
  const float* bk  = (const float*)d_in[8];
  const float* Wv  = (const float*)d_in[9];
  const float* bv  = (const float*)d_in[10];
  const float* Wo  = (const float*)d_in[11];
  const float* bo  = (const float*)d_in[12];
  const float* gq  = (const float*)d_in[13];
  const float* gk  = (const float*)d_in[14];
  const int* nmod  = (const int*)d_in[15];
  float* out = (float*)d_out;

  char* ws = (char*)d_ws;
  __hip_bfloat16* xb   = (__hip_bfloat16*)(ws + 0);           // [7168][1536]
  __hip_bfloat16* wb   = (__hip_bfloat16*)(ws + 22020096);    // [4608][1536]
  __hip_bfloat16* wob  = (__hip_bfloat16*)(ws + 36175872);    // [1536][1536]
  __hip_bfloat16* qbuf = (__hip_bfloat16*)(ws + 40894464);    // [48][1792][128]
  __hip_bfloat16* kbuf = (__hip_bfloat16*)(ws + 62914560);    // [48][1792][128]
  __hip_bfloat16* vtb  = (__hip_bfloat16*)(ws + 84934656);    // [48][128][1792]
  __hip_bfloat16* ob   = xb;                                  // O reuses xb region

  cast_kernel<<<(11010048 / 4 + 255) / 256, 256, 0, stream>>>(x, xb, 11010048 / 4);
  cast_kernel<<<(2359296 / 4 + 255) / 256, 256, 0, stream>>>(Wq, wb, 2359296 / 4);
  cast_kernel<<<(2359296 / 4 + 255) / 256, 256, 0, stream>>>(Wk, wb + 2359296, 2359296 / 4);
  cast_kernel<<<(2359296 / 4 + 255) / 256, 256, 0, stream>>>(Wv, wb + 4718592, 2359296 / 4);
  cast_kernel<<<(2359296 / 4 + 255) / 256, 256, 0, stream>>>(Wo, wob, 2359296 / 4);

  gemm_bt<0><<<dim3(36, 56), 256, 0, stream>>>(xb, wb, 1536, bq, bk, bv,
                                               qbuf, kbuf, vtb, nullptr, nullptr);
  rmsrope_kernel<<<7168, 256, 0, stream>>>(qbuf, kbuf, gq, gk, fc, fs, grid_sizes, nmod);
  attn_kernel<<<672, 256, 0, stream>>>(qbuf, kbuf, vtb, seq_lens, ob);
  gemm_bt<1><<<dim3(12, 56), 256, 0, stream>>>(ob, wob, 1536, nullptr, nullptr, nullptr,
                                               nullptr, nullptr, nullptr, bo, out);
}

// Round 5
// 686.957 us; speedup vs baseline: 1.0204x; 1.0204x over previous
//
#include <hip/hip_runtime.h>
#include <hip/hip_bf16.h>

typedef short bf16x8 __attribute__((ext_vector_type(8)));
typedef float f32x4 __attribute__((ext_vector_type(4)));
typedef float f32x16 __attribute__((ext_vector_type(16)));

#define NH 12
#define SEQ 1792
#define DMODEL 1536
#define HD 128

static __device__ __forceinline__ void gload16(const void* g, void* l) {
  __builtin_amdgcn_global_load_lds((const __attribute__((address_space(1))) void*)g,
                                   (__attribute__((address_space(3))) void*)l, 16, 0, 0);
}

static __device__ __forceinline__ short f2bf(float x) {
  __hip_bfloat16 h = __float2bfloat16(x);
  return *reinterpret_cast<short*>(&h);
}

static __device__ __forceinline__ unsigned pack2(float lo, float hi) {
  unsigned a = (unsigned)(unsigned short)f2bf(lo);
  unsigned b = (unsigned)(unsigned short)f2bf(hi);
  return a | (b << 16);
}

// ---------- fp32 -> bf16 cast, x4 vectorized ----------
__global__ __launch_bounds__(256) void cast_kernel(const float* __restrict__ src,
                                                   __hip_bfloat16* __restrict__ dst, int n4) {
  int i = blockIdx.x * 256 + threadIdx.x;
  if (i >= n4) return;
  float4 v = reinterpret_cast<const float4*>(src)[i];
  short4 r;
  r.x = f2bf(v.x); r.y = f2bf(v.y); r.z = f2bf(v.z); r.w = f2bf(v.w);
  reinterpret_cast<short4*>(dst)[i] = r;
}

// ---------- 128x128 bf16 GEMM, B^T layout (C = A @ B^T), m97 structure ----------
template<int MODE>
__global__ __launch_bounds__(256) void gemm_bt(
    const __hip_bfloat16* __restrict__ A, const __hip_bfloat16* __restrict__ B, int K,
    const float* __restrict__ bq, const float* __restrict__ bk, const float* __restrict__ bv,
    __hip_bfloat16* __restrict__ qbuf, __hip_bfloat16* __restrict__ kbuf,
    __hip_bfloat16* __restrict__ vt,
    const float* __restrict__ bo, float* __restrict__ outp)
{
  __shared__ __hip_bfloat16 Abuf[2][128 * 32];
  __shared__ __hip_bfloat16 Bbuf[2][128 * 32];
  const int tid = threadIdx.x;
  const int l = tid & 63, w = tid >> 6;
  const int lr = l & 15, lg = l >> 4;
  const int wr = w >> 1, wc = w & 1;
  const int m0 = blockIdx.y * 128, n0 = blockIdx.x * 128;
  const int nK = K >> 5;

  f32x4 acc[4][4] = {};

  auto stage = [&](int buf, int kk) {
#pragma unroll
    for (int q2 = 0; q2 < 2; ++q2) {
      int flat = q2 * 256 + tid;
      int row = flat >> 2;
      int kb16 = (flat & 3) * 16;
      const __hip_bfloat16* ga = A + (size_t)(m0 + row) * K + kk + (kb16 >> 1);
      gload16(ga, &Abuf[buf][(q2 * 256 + w * 64) * 8]);
      const __hip_bfloat16* gb = B + (size_t)(n0 + row) * K + kk + (kb16 >> 1);
      gload16(gb, &Bbuf[buf][(q2 * 256 + w * 64) * 8]);
    }
  };

  stage(0, 0);
  for (int kt = 0; kt < nK; ++kt) {
    __syncthreads();
    if (kt + 1 < nK) stage((kt + 1) & 1, (kt + 1) * 32);
    const __hip_bfloat16* Ab = Abuf[kt & 1];
    const __hip_bfloat16* Bb = Bbuf[kt & 1];
    bf16x8 af[4], bfr[4];
#pragma unroll
    for (int fi = 0; fi < 4; ++fi)
      af[fi] = *reinterpret_cast<const bf16x8*>(&Ab[(wr * 64 + fi * 16 + lr) * 32 + lg * 8]);
#pragma unroll
    for (int fj = 0; fj < 4; ++fj)
      bfr[fj] = *reinterpret_cast<const bf16x8*>(&Bb[(wc * 64 + fj * 16 + lr) * 32 + lg * 8]);
#pragma unroll
    for (int fi = 0; fi < 4; ++fi)
#pragma unroll
      for (int fj = 0; fj < 4; ++fj)
        acc[fi][fj] = __builtin_amdgcn_mfma_f32_16x16x32_bf16(af[fi], bfr[fj], acc[fi][fj], 0, 0, 0);
  }

  if (MODE == 0) {
#pragma unroll
    for (int fj = 0; fj < 4; ++fj) {
      int ncol = n0 + wc * 64 + fj * 16 + lr;
      int which = ncol / DMODEL;
      int cc = ncol - which * DMODEL;
      int hh = cc >> 7, dd = cc & 127;
      float bias = (which == 0 ? bq : which == 1 ? bk : bv)[cc];
#pragma unroll
      for (int fi = 0; fi < 4; ++fi)
#pragma unroll
        for (int r = 0; r < 4; ++r) {
          int rowg = m0 + wr * 64 + fi * 16 + lg * 4 + r;
          int bbb = rowg / SEQ;
          int sr = rowg - bbb * SEQ;
          __hip_bfloat16 hv = __float2bfloat16(acc[fi][fj][r] + bias);
          if (which == 0)
            qbuf[(((size_t)(bbb * NH + hh)) * SEQ + sr) * HD + dd] = hv;
          else if (which == 1)
            kbuf[(((size_t)(bbb * NH + hh)) * SEQ + sr) * HD + dd] = hv;
          else
            vt[(((size_t)(bbb * NH + hh)) * HD + dd) * SEQ + sr] = hv;
        }
    }
  } else {
#pragma unroll
    for (int fj = 0; fj < 4; ++fj) {
      int ncol = n0 + wc * 64 + fj * 16 + lr;
      float bias = bo[ncol];
#pragma unroll
      for (int fi = 0; fi < 4; ++fi)
#pragma unroll
        for (int r = 0; r < 4; ++r) {
          int rowg = m0 + wr * 64 + fi * 16 + lg * 4 + r;
          outp[(size_t)rowg * DMODEL + ncol] = acc[fi][fj][r] + bias;
        }
    }
  }
}

// ---------- RMSNorm (full-D) + 3D-grid RoPE, in-place on q,k ----------
// q additionally pre-scaled by 1/sqrt(HD) so attention skips the scale.
__global__ __launch_bounds__(256) void rmsrope_kernel(
    __hip_bfloat16* __restrict__ qb, __hip_bfloat16* __restrict__ kb,
    const float* __restrict__ gq, const float* __restrict__ gk,
    const float* __restrict__ fc, const float* __restrict__ fs,
    const int* __restrict__ gsz, const int* __restrict__ nmod)
{
  const int bs = blockIdx.x;
  const int b = bs / SEQ, s = bs - b * SEQ;
  const int t = threadIdx.x;
  const int f = gsz[0], h = gsz[1], wd = gsz[2];
  const int mm = nmod[0];
  const int seq_per = f * h * wd;
  int total_len = seq_per * mm; if (total_len > SEQ) total_len = SEQ;
  const bool dorope = s < total_len;
  int fi = 0, hi2 = 0, wi = 0;
  if (dorope) {
    int p = s % seq_per;
    fi = p / (h * wd);
    int rem = p - fi * (h * wd);
    hi2 = rem / wd;
    wi = rem - hi2 * wd;
  }
  float qv[3][2], kv[3][2];
  float sq = 0.f, sk = 0.f;
#pragma unroll
  for (int r = 0; r < 3; ++r) {
    int pi = t + r * 256;
    int head = pi >> 6;
    int dd = (pi & 63) * 2;
    size_t addr = (((size_t)(b * NH + head)) * SEQ + s) * HD + dd;
    __hip_bfloat162 q2 = *reinterpret_cast<const __hip_bfloat162*>(&qb[addr]);
    __hip_bfloat162 k2 = *reinterpret_cast<const __hip_bfloat162*>(&kb[addr]);
    qv[r][0] = __bfloat162float(q2.x); qv[r][1] = __bfloat162float(q2.y);
    kv[r][0] = __bfloat162float(k2.x); kv[r][1] = __bfloat162float(k2.y);
    sq += qv[r][0] * qv[r][0] + qv[r][1] * qv[r][1];
    sk += kv[r][0] * kv[r][0] + kv[r][1] * kv[r][1];
  }
#pragma unroll
  for (int off = 1; off < 64; off <<= 1) {
    sq += __shfl_xor(sq, off);
    sk += __shfl_xor(sk, off);
  }
  __shared__ float red[2][4];
  if ((t & 63) == 0) { red[0][t >> 6] = sq; red[1][t >> 6] = sk; }
  __syncthreads();
  float tq = red[0][0] + red[0][1] + red[0][2] + red[0][3];
  float tk = red[1][0] + red[1][1] + red[1][2] + red[1][3];
  float rq = rsqrtf(tq * (1.0f / DMODEL) + 1e-6f);
  float rk = rsqrtf(tk * (1.0f / DMODEL) + 1e-6f);
  const float scale = 0.08838834764831845f; // 1/sqrt(128), folded into q
#pragma unroll
  for (int r = 0; r < 3; ++r) {
    int pi = t + r * 256;
    int head = pi >> 6;
    int dd = (pi & 63) * 2;
    int col = pi * 2;
    size_t addr = (((size_t)(b * NH + head)) * SEQ + s) * HD + dd;
    float q0 = qv[r][0] * rq * gq[col], q1 = qv[r][1] * rq * gq[col + 1];
    float k0 = kv[r][0] * rk * gk[col], k1 = kv[r][1] * rk * gk[col + 1];
    if (dorope) {
      int j = pi & 63;
      int row = (j < 22) ? fi : (j < 43) ? hi2 : wi;
      float co = fc[row * 64 + j], si = fs[row * 64 + j];
      float a;
      a = q0 * co - q1 * si; q1 = q0 * si + q1 * co; q0 = a;
      a = k0 * co - k1 * si; k1 = k0 * si + k1 * co; k0 = a;
    }
    q0 *= scale; q1 *= scale;
    __hip_bfloat162 oq, ok;
    oq.x = __float2bfloat16(q0); oq.y = __float2bfloat16(q1);
    ok.x = __float2bfloat16(k0); ok.y = __float2bfloat16(k1);
    *reinterpret_cast<__hip_bfloat162*>(&qb[addr]) = oq;
    *reinterpret_cast<__hip_bfloat162*>(&kb[addr]) = ok;
  }
}

// ---------- flash attention v5: 4 waves x QBLK=32 (128 q-rows/block) ----------
// R3 structure (K LDS dbuf XOR-swizzled, swapped QK^T, in-reg softmax, defer-max,
// V direct global) at finer block granularity for TLP: grid 672 = 8 x 84
// (bijective XCD swizzle, 6 whole heads per XCD), ~2.6 blocks/CU co-resident.
__global__ __launch_bounds__(256, 4) void attn_kernel(
    const __hip_bfloat16* __restrict__ qb, const __hip_bfloat16* __restrict__ kbuf,
    const __hip_bfloat16* __restrict__ vt, const int* __restrict__ seq_lens,
    __hip_bfloat16* __restrict__ ob)
{
  const int orig = blockIdx.x;
  const int wg = (orig & 7) * 84 + (orig >> 3);
  const int bh = wg / 14, qt = wg % 14;
  const int bbb = bh / NH, hh = bh - bbb * NH;
  const int tid = threadIdx.x;
  const int w = tid >> 6, l = tid & 63;
  const int lq = l & 31, h = l >> 5;
  const int sl = seq_lens[bbb];
  const __hip_bfloat16* Q = qb + (size_t)bh * SEQ * HD;
  const char* Kc = (const char*)(kbuf + (size_t)bh * SEQ * HD);
  const __hip_bfloat16* Vp = vt + (size_t)bh * HD * SEQ;   // [128][1792]
  const int q0 = qt * 128 + w * 32;

  __shared__ __hip_bfloat16 Kt[2][64 * 128];   // swizzled: byte ^= ((row&7)<<4)

  // Q fragments (B-operand of swapped QK^T): lane holds Q[q0+lq][kc*16 + h*8 + j]
  bf16x8 qf[8];
#pragma unroll
  for (int kc = 0; kc < 8; ++kc)
    qf[kc] = *reinterpret_cast<const bf16x8*>(
        &Q[(size_t)(q0 + lq) * HD + kc * 16 + h * 8]);

  f32x16 oacc[4] = {};                          // O[q_off][d0*32+lq]
  float m = -3e38f, ll = 0.f;                   // per-lane q-row softmax state

  const int nkt = (sl + 63) >> 6;

  auto stageK = [&](int buf, int k0) {
    char* Lb = (char*)&Kt[buf][0];
#pragma unroll
    for (int q2 = 0; q2 < 4; ++q2) {
      int chunk = q2 * 256 + w * 64 + l;        // 16B chunk id in [0,1024)
      int row = chunk >> 4;                     // 16 chunks per 256B row
      int cb = (chunk & 15) << 4;
      int scb = cb ^ ((row & 7) << 4);          // inverse-swizzled source
      gload16(Kc + (size_t)(k0 + row) * 256 + scb, Lb + (q2 * 256 + w * 64) * 16);
    }
  };

  stageK(0, 0);
  for (int kt = 0; kt < nkt; ++kt) {
    __syncthreads();                            // stage(kt) drained
    const int k0 = kt * 64;
    if (kt + 1 < nkt) stageK((kt + 1) & 1, k0 + 64);
    const char* Kl = (const char*)&Kt[kt & 1][0];

    // swapped QK^T: S^T[k][q], 16 ds_read_b128 + 16 mfma_32x32x16
    f32x16 sa[2] = {};
#pragma unroll
    for (int cb = 0; cb < 2; ++cb) {
      int row = cb * 32 + lq;
      int swz = (row & 7) << 4;
#pragma unroll
      for (int kc = 0; kc < 8; ++kc) {
        bf16x8 kf = *reinterpret_cast<const bf16x8*>(
            Kl + row * 256 + ((kc * 32 + h * 16) ^ swz));
        sa[cb] = __builtin_amdgcn_mfma_f32_32x32x16_bf16(kf, qf[kc], sa[cb], 0, 0, 0);
      }
    }

    // mask tail (rare): k of sa[cb][r] = k0 + cb*32 + (r&3) + 8*(r>>2) + 4*h
    if (k0 + 64 > sl) {
#pragma unroll
      for (int cb = 0; cb < 2; ++cb)
#pragma unroll
        for (int r = 0; r < 16; ++r) {
          int kg = k0 + cb * 32 + (r & 3) + 8 * (r >> 2) + 4 * h;
          if (kg >= sl) sa[cb][r] = -3e38f;
        }
    }

    // in-register online softmax: lane owns q-row (lq), halves split across h
    float mx = -3e38f;
#pragma unroll
    for (int cb = 0; cb < 2; ++cb)
#pragma unroll
      for (int r = 0; r < 16; ++r) mx = fmaxf(mx, sa[cb][r]);
    mx = fmaxf(mx, __shfl_xor(mx, 32));

    if (__any(mx - m > 8.f)) {                  // defer-max (T13)
      float mn = fmaxf(m, mx);
      float alpha = __expf(m - mn);
      m = mn;
      ll *= alpha;
#pragma unroll
      for (int r = 0; r < 16; ++r) {
        float ar = __shfl(alpha, (r & 3) + 8 * (r >> 2) + 4 * h);
#pragma unroll
        for (int d0 = 0; d0 < 4; ++d0) oacc[d0][r] *= ar;
      }
    }

    float rs = 0.f;
#pragma unroll
    for (int cb = 0; cb < 2; ++cb)
#pragma unroll
      for (int r = 0; r < 16; ++r) {
        float e = __expf(sa[cb][r] - m);
        sa[cb][r] = e;
        rs += e;
      }
    rs += __shfl_xor(rs, 32);
    ll += rs;

    // P -> bf16 A-frags (pack + shfl_xor(32) exchange) and PV
#pragma unroll
    for (int c = 0; c < 4; ++c) {
      const int cb = c >> 1, r0 = 8 * (c & 1);
      unsigned A01 = pack2(sa[cb][r0],     sa[cb][r0 + 1]);
      unsigned A23 = pack2(sa[cb][r0 + 2], sa[cb][r0 + 3]);
      unsigned B01 = pack2(sa[cb][r0 + 4], sa[cb][r0 + 5]);
      unsigned B23 = pack2(sa[cb][r0 + 6], sa[cb][r0 + 7]);
      unsigned s1 = __shfl_xor(h ? A01 : B01, 32);
      unsigned s2 = __shfl_xor(h ? A23 : B23, 32);
      int4 wv;
      wv.x = (int)(h ? s1 : A01);
      wv.y = (int)(h ? s2 : A23);
      wv.z = (int)(h ? B01 : s1);
      wv.w = (int)(h ? B23 : s2);
      bf16x8 pa = *reinterpret_cast<bf16x8*>(&wv);
#pragma unroll
      for (int d0 = 0; d0 < 4; ++d0) {
        bf16x8 vv = *reinterpret_cast<const bf16x8*>(
            &Vp[(size_t)(d0 * 32 + lq) * SEQ + k0 + c * 16 + h * 8]);
        oacc[d0] = __builtin_amdgcn_mfma_f32_32x32x16_bf16(pa, vv, oacc[d0], 0, 0, 0);
      }
    }
  }

  // epilogue: normalize by per-q-row sum, write O
  float invl = 1.0f / ll;
#pragma unroll
  for (int r = 0; r < 16; ++r) {
    int qoff = (r & 3) + 8 * (r >> 2) + 4 * h;
    float ir = __shfl(invl, qoff);
    int qrow = q0 + qoff;
#pragma unroll
    for (int d0 = 0; d0 < 4; ++d0)
      ob[((size_t)bbb * SEQ + qrow) * DMODEL + hh * HD + d0 * 32 + lq] =
          __float2bfloat16(oacc[d0][r] * ir);
  }
}

// ---------- launch ----------
extern "C" void kernel_launch(void* const* d_in, const int* in_sizes, int n_in,
                              void* d_out, int out_size, void* d_ws, size_t ws_size,
                              hipStream_t stream) {
  const float* x   = (const float*)d_in[0];
  const int* seq_lens   = (const int*)d_in[1];
  const int* grid_sizes = (const int*)d_in[2];
  const float* fc  = (const float*)d_in[3];
  const float* fs  = (const float*)d_in[4];
  const float* Wq  = (const float*)d_in[5];
  const float* bq  = (const float*)d_in[6];
  const float* Wk  = (const float*)d_in[7];
  const float* bk  = (const float*)d_in[8];
  const float* Wv  = (const float*)d_in[9];
  const float* bv  = (const float*)d_in[10];
  const float* Wo  = (const float*)d_in[11];
  const float* bo  = (const float*)d_in[12];
  const float* gq  = (const float*)d_in[13];
  const float* gk  = (const float*)d_in[14];
  const int* nmod  = (const int*)d_in[15];
  float* out = (float*)d_out;

  char* ws = (char*)d_ws;
  __hip_bfloat16* xb   = (__hip_bfloat16*)(ws + 0);           // [7168][1536]
  __hip_bfloat16* wb   = (__hip_bfloat16*)(ws + 22020096);    // [4608][1536]
  __hip_bfloat16* wob  = (__hip_bfloat16*)(ws + 36175872);    // [1536][1536]
  __hip_bfloat16* qbuf = (__hip_bfloat16*)(ws + 40894464);    // [48][1792][128]
  __hip_bfloat16* kbuf = (__hip_bfloat16*)(ws + 62914560);    // [48][1792][128]
  __hip_bfloat16* vtb  = (__hip_bfloat16*)(ws + 84934656);    // [48][128][1792]
  __hip_bfloat16* ob   = xb;                                  // O reuses xb region

  cast_kernel<<<(11010048 / 4 + 255) / 256, 256, 0, stream>>>(x, xb, 11010048 / 4);
  cast_kernel<<<(2359296 / 4 + 255) / 256, 256, 0, stream>>>(Wq, wb, 2359296 / 4);
  cast_kernel<<<(2359296 / 4 + 255) / 256, 256, 0, stream>>>(Wk, wb + 2359296, 2359296 / 4);
  cast_kernel<<<(2359296 / 4 + 255) / 256, 256, 0, stream>>>(Wv, wb + 4718592, 2359296 / 4);
  cast_kernel<<<(2359296 / 4 + 255) / 256, 256, 0, stream>>>(Wo, wob, 2359296 / 4);

  gemm_bt<0><<<dim3(36, 56), 256, 0, stream>>>(xb, wb, 1536, bq, bk, bv,
                                               qbuf, kbuf, vtb, nullptr, nullptr);
  rmsrope_kernel<<<7168, 256, 0, stream>>>(qbuf, kbuf, gq, gk, fc, fs, grid_sizes, nmod);
  attn_kernel<<<672, 256, 0, stream>>>(qbuf, kbuf, vtb, seq_lens, ob);
  gemm_bt<1><<<dim3(12, 56), 256, 0, stream>>>(ob, wob, 1536, nullptr, nullptr, nullptr,
                                               nullptr, nullptr, nullptr, bo, out);
}

// Round 6
// 472.497 us; speedup vs baseline: 1.4836x; 1.4539x over previous
//
#include <hip/hip_runtime.h>
#include <hip/hip_bf16.h>

typedef short bf16x8 __attribute__((ext_vector_type(8)));
typedef float f32x4 __attribute__((ext_vector_type(4)));
typedef float f32x16 __attribute__((ext_vector_type(16)));

#define NH 12
#define SEQ 1792
#define DMODEL 1536
#define HD 128

static __device__ __forceinline__ void gload16(const void* g, void* l) {
  __builtin_amdgcn_global_load_lds((const __attribute__((address_space(1))) void*)g,
                                   (__attribute__((address_space(3))) void*)l, 16, 0, 0);
}

static __device__ __forceinline__ short f2bf(float x) {
  __hip_bfloat16 h = __float2bfloat16(x);
  return *reinterpret_cast<short*>(&h);
}

static __device__ __forceinline__ unsigned pack2(float lo, float hi) {
  unsigned a = (unsigned)(unsigned short)f2bf(lo);
  unsigned b = (unsigned)(unsigned short)f2bf(hi);
  return a | (b << 16);
}

// ---------- fp32 -> bf16 cast, x4 vectorized ----------
__global__ __launch_bounds__(256) void cast_kernel(const float* __restrict__ src,
                                                   __hip_bfloat16* __restrict__ dst, int n4) {
  int i = blockIdx.x * 256 + threadIdx.x;
  if (i >= n4) return;
  float4 v = reinterpret_cast<const float4*>(src)[i];
  short4 r;
  r.x = f2bf(v.x); r.y = f2bf(v.y); r.z = f2bf(v.z); r.w = f2bf(v.w);
  reinterpret_cast<short4*>(dst)[i] = r;
}

// ---------- 128x128 bf16 GEMM, B^T layout (C = A @ B^T), m97 structure ----------
template<int MODE>
__global__ __launch_bounds__(256) void gemm_bt(
    const __hip_bfloat16* __restrict__ A, const __hip_bfloat16* __restrict__ B, int K,
    const float* __restrict__ bq, const float* __restrict__ bk, const float* __restrict__ bv,
    __hip_bfloat16* __restrict__ qbuf, __hip_bfloat16* __restrict__ kbuf,
    __hip_bfloat16* __restrict__ vt,
    const float* __restrict__ bo, float* __restrict__ outp)
{
  __shared__ __hip_bfloat16 Abuf[2][128 * 32];
  __shared__ __hip_bfloat16 Bbuf[2][128 * 32];
  const int tid = threadIdx.x;
  const int l = tid & 63, w = tid >> 6;
  const int lr = l & 15, lg = l >> 4;
  const int wr = w >> 1, wc = w & 1;
  const int m0 = blockIdx.y * 128, n0 = blockIdx.x * 128;
  const int nK = K >> 5;

  f32x4 acc[4][4] = {};

  auto stage = [&](int buf, int kk) {
#pragma unroll
    for (int q2 = 0; q2 < 2; ++q2) {
      int flat = q2 * 256 + tid;
      int row = flat >> 2;
      int kb16 = (flat & 3) * 16;
      const __hip_bfloat16* ga = A + (size_t)(m0 + row) * K + kk + (kb16 >> 1);
      gload16(ga, &Abuf[buf][(q2 * 256 + w * 64) * 8]);
      const __hip_bfloat16* gb = B + (size_t)(n0 + row) * K + kk + (kb16 >> 1);
      gload16(gb, &Bbuf[buf][(q2 * 256 + w * 64) * 8]);
    }
  };

  stage(0, 0);
  for (int kt = 0; kt < nK; ++kt) {
    __syncthreads();
    if (kt + 1 < nK) stage((kt + 1) & 1, (kt + 1) * 32);
    const __hip_bfloat16* Ab = Abuf[kt & 1];
    const __hip_bfloat16* Bb = Bbuf[kt & 1];
    bf16x8 af[4], bfr[4];
#pragma unroll
    for (int fi = 0; fi < 4; ++fi)
      af[fi] = *reinterpret_cast<const bf16x8*>(&Ab[(wr * 64 + fi * 16 + lr) * 32 + lg * 8]);
#pragma unroll
    for (int fj = 0; fj < 4; ++fj)
      bfr[fj] = *reinterpret_cast<const bf16x8*>(&Bb[(wc * 64 + fj * 16 + lr) * 32 + lg * 8]);
#pragma unroll
    for (int fi = 0; fi < 4; ++fi)
#pragma unroll
      for (int fj = 0; fj < 4; ++fj)
        acc[fi][fj] = __builtin_amdgcn_mfma_f32_16x16x32_bf16(af[fi], bfr[fj], acc[fi][fj], 0, 0, 0);
  }

  if (MODE == 0) {
#pragma unroll
    for (int fj = 0; fj < 4; ++fj) {
      int ncol = n0 + wc * 64 + fj * 16 + lr;
      int which = ncol / DMODEL;
      int cc = ncol - which * DMODEL;
      int hh = cc >> 7, dd = cc & 127;
      float bias = (which == 0 ? bq : which == 1 ? bk : bv)[cc];
#pragma unroll
      for (int fi = 0; fi < 4; ++fi)
#pragma unroll
        for (int r = 0; r < 4; ++r) {
          int rowg = m0 + wr * 64 + fi * 16 + lg * 4 + r;
          int bbb = rowg / SEQ;
          int sr = rowg - bbb * SEQ;
          __hip_bfloat16 hv = __float2bfloat16(acc[fi][fj][r] + bias);
          if (which == 0)
            qbuf[(((size_t)(bbb * NH + hh)) * SEQ + sr) * HD + dd] = hv;
          else if (which == 1)
            kbuf[(((size_t)(bbb * NH + hh)) * SEQ + sr) * HD + dd] = hv;
          else
            vt[(((size_t)(bbb * NH + hh)) * HD + dd) * SEQ + sr] = hv;
        }
    }
  } else {
#pragma unroll
    for (int fj = 0; fj < 4; ++fj) {
      int ncol = n0 + wc * 64 + fj * 16 + lr;
      float bias = bo[ncol];
#pragma unroll
      for (int fi = 0; fi < 4; ++fi)
#pragma unroll
        for (int r = 0; r < 4; ++r) {
          int rowg = m0 + wr * 64 + fi * 16 + lg * 4 + r;
          outp[(size_t)rowg * DMODEL + ncol] = acc[fi][fj][r] + bias;
        }
    }
  }
}

// ---------- RMSNorm (full-D) + 3D-grid RoPE, in-place on q,k ----------
// q additionally pre-scaled by 1/sqrt(HD) so attention skips the scale.
__global__ __launch_bounds__(256) void rmsrope_kernel(
    __hip_bfloat16* __restrict__ qb, __hip_bfloat16* __restrict__ kb,
    const float* __restrict__ gq, const float* __restrict__ gk,
    const float* __restrict__ fc, const float* __restrict__ fs,
    const int* __restrict__ gsz, const int* __restrict__ nmod)
{
  const int bs = blockIdx.x;
  const int b = bs / SEQ, s = bs - b * SEQ;
  const int t = threadIdx.x;
  const int f = gsz[0], h = gsz[1], wd = gsz[2];
  const int mm = nmod[0];
  const int seq_per = f * h * wd;
  int total_len = seq_per * mm; if (total_len > SEQ) total_len = SEQ;
  const bool dorope = s < total_len;
  int fi = 0, hi2 = 0, wi = 0;
  if (dorope) {
    int p = s % seq_per;
    fi = p / (h * wd);
    int rem = p - fi * (h * wd);
    hi2 = rem / wd;
    wi = rem - hi2 * wd;
  }
  float qv[3][2], kv[3][2];
  float sq = 0.f, sk = 0.f;
#pragma unroll
  for (int r = 0; r < 3; ++r) {
    int pi = t + r * 256;
    int head = pi >> 6;
    int dd = (pi & 63) * 2;
    size_t addr = (((size_t)(b * NH + head)) * SEQ + s) * HD + dd;
    __hip_bfloat162 q2 = *reinterpret_cast<const __hip_bfloat162*>(&qb[addr]);
    __hip_bfloat162 k2 = *reinterpret_cast<const __hip_bfloat162*>(&kb[addr]);
    qv[r][0] = __bfloat162float(q2.x); qv[r][1] = __bfloat162float(q2.y);
    kv[r][0] = __bfloat162float(k2.x); kv[r][1] = __bfloat162float(k2.y);
    sq += qv[r][0] * qv[r][0] + qv[r][1] * qv[r][1];
    sk += kv[r][0] * kv[r][0] + kv[r][1] * kv[r][1];
  }
#pragma unroll
  for (int off = 1; off < 64; off <<= 1) {
    sq += __shfl_xor(sq, off);
    sk += __shfl_xor(sk, off);
  }
  __shared__ float red[2][4];
  if ((t & 63) == 0) { red[0][t >> 6] = sq; red[1][t >> 6] = sk; }
  __syncthreads();
  float tq = red[0][0] + red[0][1] + red[0][2] + red[0][3];
  float tk = red[1][0] + red[1][1] + red[1][2] + red[1][3];
  float rq = rsqrtf(tq * (1.0f / DMODEL) + 1e-6f);
  float rk = rsqrtf(tk * (1.0f / DMODEL) + 1e-6f);
  const float scale = 0.08838834764831845f; // 1/sqrt(128), folded into q
#pragma unroll
  for (int r = 0; r < 3; ++r) {
    int pi = t + r * 256;
    int head = pi >> 6;
    int dd = (pi & 63) * 2;
    int col = pi * 2;
    size_t addr = (((size_t)(b * NH + head)) * SEQ + s) * HD + dd;
    float q0 = qv[r][0] * rq * gq[col], q1 = qv[r][1] * rq * gq[col + 1];
    float k0 = kv[r][0] * rk * gk[col], k1 = kv[r][1] * rk * gk[col + 1];
    if (dorope) {
      int j = pi & 63;
      int row = (j < 22) ? fi : (j < 43) ? hi2 : wi;
      float co = fc[row * 64 + j], si = fs[row * 64 + j];
      float a;
      a = q0 * co - q1 * si; q1 = q0 * si + q1 * co; q0 = a;
      a = k0 * co - k1 * si; k1 = k0 * si + k1 * co; k0 = a;
    }
    q0 *= scale; q1 *= scale;
    __hip_bfloat162 oq, ok;
    oq.x = __float2bfloat16(q0); oq.y = __float2bfloat16(q1);
    ok.x = __float2bfloat16(k0); ok.y = __float2bfloat16(k1);
    *reinterpret_cast<__hip_bfloat162*>(&qb[addr]) = oq;
    *reinterpret_cast<__hip_bfloat162*>(&kb[addr]) = ok;
  }
}

// ---------- flash attention v6: 4 waves x QBLK=32 (128 q-rows/block) ----------
// R5 structure with the spill-fix: __launch_bounds__(256, 2) (cap 256 regs).
// R5's (256,4) capped unified regs at 128 -> ~44 hot spills -> 462 MB scratch
// writes. Per-thread state needs ~172 (108 arch + 64 acc); (256,2) fits it.
__global__ __launch_bounds__(256, 2) void attn_kernel(
    const __hip_bfloat16* __restrict__ qb, const __hip_bfloat16* __restrict__ kbuf,
    const __hip_bfloat16* __restrict__ vt, const int* __restrict__ seq_lens,
    __hip_bfloat16* __restrict__ ob)
{
  const int orig = blockIdx.x;
  const int wg = (orig & 7) * 84 + (orig >> 3);
  const int bh = wg / 14, qt = wg % 14;
  const int bbb = bh / NH, hh = bh - bbb * NH;
  const int tid = threadIdx.x;
  const int w = tid >> 6, l = tid & 63;
  const int lq = l & 31, h = l >> 5;
  const int sl = seq_lens[bbb];
  const __hip_bfloat16* Q = qb + (size_t)bh * SEQ * HD;
  const char* Kc = (const char*)(kbuf + (size_t)bh * SEQ * HD);
  const __hip_bfloat16* Vp = vt + (size_t)bh * HD * SEQ;   // [128][1792]
  const int q0 = qt * 128 + w * 32;

  __shared__ __hip_bfloat16 Kt[2][64 * 128];   // swizzled: byte ^= ((row&7)<<4)

  // Q fragments (B-operand of swapped QK^T): lane holds Q[q0+lq][kc*16 + h*8 + j]
  bf16x8 qf[8];
#pragma unroll
  for (int kc = 0; kc < 8; ++kc)
    qf[kc] = *reinterpret_cast<const bf16x8*>(
        &Q[(size_t)(q0 + lq) * HD + kc * 16 + h * 8]);

  f32x16 oacc[4] = {};                          // O[q_off][d0*32+lq]
  float m = -3e38f, ll = 0.f;                   // per-lane q-row softmax state

  const int nkt = (sl + 63) >> 6;

  auto stageK = [&](int buf, int k0) {
    char* Lb = (char*)&Kt[buf][0];
#pragma unroll
    for (int q2 = 0; q2 < 4; ++q2) {
      int chunk = q2 * 256 + w * 64 + l;        // 16B chunk id in [0,1024)
      int row = chunk >> 4;                     // 16 chunks per 256B row
      int cb = (chunk & 15) << 4;
      int scb = cb ^ ((row & 7) << 4);          // inverse-swizzled source
      gload16(Kc + (size_t)(k0 + row) * 256 + scb, Lb + (q2 * 256 + w * 64) * 16);
    }
  };

  stageK(0, 0);
  for (int kt = 0; kt < nkt; ++kt) {
    __syncthreads();                            // stage(kt) drained
    const int k0 = kt * 64;
    if (kt + 1 < nkt) stageK((kt + 1) & 1, k0 + 64);
    const char* Kl = (const char*)&Kt[kt & 1][0];

    // swapped QK^T: S^T[k][q], 16 ds_read_b128 + 16 mfma_32x32x16
    f32x16 sa[2] = {};
#pragma unroll
    for (int cb = 0; cb < 2; ++cb) {
      int row = cb * 32 + lq;
      int swz = (row & 7) << 4;
#pragma unroll
      for (int kc = 0; kc < 8; ++kc) {
        bf16x8 kf = *reinterpret_cast<const bf16x8*>(
            Kl + row * 256 + ((kc * 32 + h * 16) ^ swz));
        sa[cb] = __builtin_amdgcn_mfma_f32_32x32x16_bf16(kf, qf[kc], sa[cb], 0, 0, 0);
      }
    }

    // mask tail (rare): k of sa[cb][r] = k0 + cb*32 + (r&3) + 8*(r>>2) + 4*h
    if (k0 + 64 > sl) {
#pragma unroll
      for (int cb = 0; cb < 2; ++cb)
#pragma unroll
        for (int r = 0; r < 16; ++r) {
          int kg = k0 + cb * 32 + (r & 3) + 8 * (r >> 2) + 4 * h;
          if (kg >= sl) sa[cb][r] = -3e38f;
        }
    }

    // in-register online softmax: lane owns q-row (lq), halves split across h
    float mx = -3e38f;
#pragma unroll
    for (int cb = 0; cb < 2; ++cb)
#pragma unroll
      for (int r = 0; r < 16; ++r) mx = fmaxf(mx, sa[cb][r]);
    mx = fmaxf(mx, __shfl_xor(mx, 32));

    if (__any(mx - m > 8.f)) {                  // defer-max (T13)
      float mn = fmaxf(m, mx);
      float alpha = __expf(m - mn);
      m = mn;
      ll *= alpha;
#pragma unroll
      for (int r = 0; r < 16; ++r) {
        float ar = __shfl(alpha, (r & 3) + 8 * (r >> 2) + 4 * h);
#pragma unroll
        for (int d0 = 0; d0 < 4; ++d0) oacc[d0][r] *= ar;
      }
    }

    float rs = 0.f;
#pragma unroll
    for (int cb = 0; cb < 2; ++cb)
#pragma unroll
      for (int r = 0; r < 16; ++r) {
        float e = __expf(sa[cb][r] - m);
        sa[cb][r] = e;
        rs += e;
      }
    rs += __shfl_xor(rs, 32);
    ll += rs;

    // P -> bf16 A-frags (pack + shfl_xor(32) exchange) and PV
#pragma unroll
    for (int c = 0; c < 4; ++c) {
      const int cb = c >> 1, r0 = 8 * (c & 1);
      unsigned A01 = pack2(sa[cb][r0],     sa[cb][r0 + 1]);
      unsigned A23 = pack2(sa[cb][r0 + 2], sa[cb][r0 + 3]);
      unsigned B01 = pack2(sa[cb][r0 + 4], sa[cb][r0 + 5]);
      unsigned B23 = pack2(sa[cb][r0 + 6], sa[cb][r0 + 7]);
      unsigned s1 = __shfl_xor(h ? A01 : B01, 32);
      unsigned s2 = __shfl_xor(h ? A23 : B23, 32);
      int4 wv;
      wv.x = (int)(h ? s1 : A01);
      wv.y = (int)(h ? s2 : A23);
      wv.z = (int)(h ? B01 : s1);
      wv.w = (int)(h ? B23 : s2);
      bf16x8 pa = *reinterpret_cast<bf16x8*>(&wv);
#pragma unroll
      for (int d0 = 0; d0 < 4; ++d0) {
        bf16x8 vv = *reinterpret_cast<const bf16x8*>(
            &Vp[(size_t)(d0 * 32 + lq) * SEQ + k0 + c * 16 + h * 8]);
        oacc[d0] = __builtin_amdgcn_mfma_f32_32x32x16_bf16(pa, vv, oacc[d0], 0, 0, 0);
      }
    }
  }

  // epilogue: normalize by per-q-row sum, write O
  float invl = 1.0f / ll;
#pragma unroll
  for (int r = 0; r < 16; ++r) {
    int qoff = (r & 3) + 8 * (r >> 2) + 4 * h;
    float ir = __shfl(invl, qoff);
    int qrow = q0 + qoff;
#pragma unroll
    for (int d0 = 0; d0 < 4; ++d0)
      ob[((size_t)bbb * SEQ + qrow) * DMODEL + hh * HD + d0 * 32 + lq] =
          __float2bfloat16(oacc[d0][r] * ir);
  }
}

// ---------- launch ----------
extern "C" void kernel_launch(void* const* d_in, const int* in_sizes, int n_in,
                              void* d_out, int out_size, void* d_ws, size_t ws_size,
                              hipStream_t stream) {
  const float* x   = (const float*)d_in[0];
  const int* seq_lens   = (const int*)d_in[1];
  const int* grid_sizes = (const int*)d_in[2];
  const float* fc  = (const float*)d_in[3];
  const float* fs  = (const float*)d_in[4];
  const float* Wq  = (const float*)d_in[5];
  const float* bq  = (const float*)d_in[6];
  const float* Wk  = (const float*)d_in[7];
  const float* bk  = (const float*)d_in[8];
  const float* Wv  = (const float*)d_in[9];
  const float* bv  = (const float*)d_in[10];
  const float* Wo  = (const float*)d_in[11];
  const float* bo  = (const float*)d_in[12];
  const float* gq  = (const float*)d_in[13];
  const float* gk  = (const float*)d_in[14];
  const int* nmod  = (const int*)d_in[15];
  float* out = (float*)d_out;

  char* ws = (char*)d_ws;
  __hip_bfloat16* xb   = (__hip_bfloat16*)(ws + 0);           // [7168][1536]
  __hip_bfloat16* wb   = (__hip_bfloat16*)(ws + 22020096);    // [4608][1536]
  __hip_bfloat16* wob  = (__hip_bfloat16*)(ws + 36175872);    // [1536][1536]
  __hip_bfloat16* qbuf = (__hip_bfloat16*)(ws + 40894464);    // [48][1792][128]
  __hip_bfloat16* kbuf = (__hip_bfloat16*)(ws + 62914560);    // [48][1792][128]
  __hip_bfloat16* vtb  = (__hip_bfloat16*)(ws + 84934656);    // [48][128][1792]
  __hip_bfloat16* ob   = xb;                                  // O reuses xb region

  cast_kernel<<<(11010048 / 4 + 255) / 256, 256, 0, stream>>>(x, xb, 11010048 / 4);
  cast_kernel<<<(2359296 / 4 + 255) / 256, 256, 0, stream>>>(Wq, wb, 2359296 / 4);
  cast_kernel<<<(2359296 / 4 + 255) / 256, 256, 0, stream>>>(Wk, wb + 2359296, 2359296 / 4);
  cast_kernel<<<(2359296 / 4 + 255) / 256, 256, 0, stream>>>(Wv, wb + 4718592, 2359296 / 4);
  cast_kernel<<<(2359296 / 4 + 255) / 256, 256, 0, stream>>>(Wo, wob, 2359296 / 4);

  gemm_bt<0><<<dim3(36, 56), 256, 0, stream>>>(xb, wb, 1536, bq, bk, bv,
                                               qbuf, kbuf, vtb, nullptr, nullptr);
  rmsrope_kernel<<<7168, 256, 0, stream>>>(qbuf, kbuf, gq, gk, fc, fs, grid_sizes, nmod);
  attn_kernel<<<672, 256, 0, stream>>>(qbuf, kbuf, vtb, seq_lens, ob);
  gemm_bt<1><<<dim3(12, 56), 256, 0, stream>>>(ob, wob, 1536, nullptr, nullptr, nullptr,
                                               nullptr, nullptr, nullptr, bo, out);
}

// Round 7
// 471.037 us; speedup vs baseline: 1.4882x; 1.0031x over previous
//
#include <hip/hip_runtime.h>
#include <hip/hip_bf16.h>

typedef short bf16x8 __attribute__((ext_vector_type(8)));
typedef float f32x4 __attribute__((ext_vector_type(4)));
typedef float f32x16 __attribute__((ext_vector_type(16)));

#define NH 12
#define SEQ 1792
#define DMODEL 1536
#define HD 128

static __device__ __forceinline__ void gload16(const void* g, void* l) {
  __builtin_amdgcn_global_load_lds((const __attribute__((address_space(1))) void*)g,
                                   (__attribute__((address_space(3))) void*)l, 16, 0, 0);
}

static __device__ __forceinline__ short f2bf(float x) {
  __hip_bfloat16 h = __float2bfloat16(x);
  return *reinterpret_cast<short*>(&h);
}

static __device__ __forceinline__ unsigned pack2(float lo, float hi) {
  unsigned a = (unsigned)(unsigned short)f2bf(lo);
  unsigned b = (unsigned)(unsigned short)f2bf(hi);
  return a | (b << 16);
}

// ---------- fp32 -> bf16 cast, x4 vectorized ----------
__global__ __launch_bounds__(256) void cast_kernel(const float* __restrict__ src,
                                                   __hip_bfloat16* __restrict__ dst, int n4) {
  int i = blockIdx.x * 256 + threadIdx.x;
  if (i >= n4) return;
  float4 v = reinterpret_cast<const float4*>(src)[i];
  short4 r;
  r.x = f2bf(v.x); r.y = f2bf(v.y); r.z = f2bf(v.z); r.w = f2bf(v.w);
  reinterpret_cast<short4*>(dst)[i] = r;
}

// ---------- 256x256 bf16 GEMM (QKV), BK=32, 4-deep LDS ring, counted vmcnt ----------
// C = A @ B^T; A[7168][1536], B[4608][1536]. Epilogue: bias + scatter q/k row-major
// per-head, v transposed. T1 (bijective XCD swizzle over 504=8*63), T3/T4 (stage
// t+2 while computing t, vmcnt(4) never 0 mid-loop, raw s_barrier), T5 (setprio).
__global__ __launch_bounds__(512, 2) void gemm256_qkv(
    const __hip_bfloat16* __restrict__ A, const __hip_bfloat16* __restrict__ B,
    const float* __restrict__ bq, const float* __restrict__ bk, const float* __restrict__ bv,
    __hip_bfloat16* __restrict__ qbuf, __hip_bfloat16* __restrict__ kbuf,
    __hip_bfloat16* __restrict__ vt)
{
  __shared__ __hip_bfloat16 Ab[4][256 * 32];   // 4 x 16 KB
  __shared__ __hip_bfloat16 Bb[4][256 * 32];   // 4 x 16 KB  (total 128 KB)
  const int tid = threadIdx.x;                 // 0..511
  const int l = tid & 63, w = tid >> 6;        // 8 waves
  const int lr = l & 15, lg = l >> 4;
  const int wr = w >> 2, wc = w & 3;           // 2 x 4 wave grid
  const int K = DMODEL, nK = K >> 5;           // 48 K-tiles of 32

  // bijective XCD swizzle: nwg = 504 = 8 * 63
  const int orig = blockIdx.x;
  const int wg = (orig & 7) * 63 + (orig >> 3);
  const int m0 = (wg / 18) * 256, n0 = (wg % 18) * 256;

  auto stage = [&](int t) {
    const int buf = t & 3, kk = t * 32;
#pragma unroll
    for (int q = 0; q < 2; ++q) {
      int chunk = q * 512 + tid;               // 0..1023 (16B chunks)
      int row = chunk >> 2;                    // 4 chunks per 64B row
      int ce = (chunk & 3) * 8;                // element offset within row
      gload16(A + (size_t)(m0 + row) * K + kk + ce, (char*)&Ab[buf][0] + chunk * 16);
      gload16(B + (size_t)(n0 + row) * K + kk + ce, (char*)&Bb[buf][0] + chunk * 16);
    }
  };

  f32x4 acc[8][4] = {};

  stage(0); stage(1);
  asm volatile("s_waitcnt vmcnt(4)" ::: "memory");   // tile 0 landed (tile 1 in flight)
  __builtin_amdgcn_s_barrier();

  for (int t = 0; t < nK; ++t) {
    __builtin_amdgcn_sched_barrier(0);
    if (t + 2 < nK) stage(t + 2);              // different buffer than t, t+1 -> race-free
    const __hip_bfloat16* Al = &Ab[t & 3][0];
    const __hip_bfloat16* Bl = &Bb[t & 3][0];
    bf16x8 af[8], bfr[4];
#pragma unroll
    for (int fi = 0; fi < 8; ++fi)
      af[fi] = *reinterpret_cast<const bf16x8*>(&Al[(wr * 128 + fi * 16 + lr) * 32 + lg * 8]);
#pragma unroll
    for (int fj = 0; fj < 4; ++fj)
      bfr[fj] = *reinterpret_cast<const bf16x8*>(&Bl[(wc * 64 + fj * 16 + lr) * 32 + lg * 8]);
    __builtin_amdgcn_s_setprio(1);
#pragma unroll
    for (int fi = 0; fi < 8; ++fi)
#pragma unroll
      for (int fj = 0; fj < 4; ++fj)
        acc[fi][fj] = __builtin_amdgcn_mfma_f32_16x16x32_bf16(af[fi], bfr[fj], acc[fi][fj], 0, 0, 0);
    __builtin_amdgcn_s_setprio(0);
    if (t + 1 < nK) {
      if (t + 2 < nK) asm volatile("s_waitcnt vmcnt(4)" ::: "memory");  // t+1 landed
      else            asm volatile("s_waitcnt vmcnt(0)" ::: "memory");  // tail: no younger loads
      __builtin_amdgcn_s_barrier();
    }
  }

  // epilogue: bias + scatter (q/k row-major per head, v transposed)
#pragma unroll
  for (int fj = 0; fj < 4; ++fj) {
    int ncol = n0 + wc * 64 + fj * 16 + lr;    // 0..4607
    int which = ncol / DMODEL;                 // uniform per block (1536 = 6*256)
    int cc = ncol - which * DMODEL;
    int hh = cc >> 7, dd = cc & 127;
    float bias = (which == 0 ? bq : which == 1 ? bk : bv)[cc];
#pragma unroll
    for (int fi = 0; fi < 8; ++fi)
#pragma unroll
      for (int r = 0; r < 4; ++r) {
        int rowg = m0 + wr * 128 + fi * 16 + lg * 4 + r;
        int bbb = rowg / SEQ;
        int sr = rowg - bbb * SEQ;
        __hip_bfloat16 hv = __float2bfloat16(acc[fi][fj][r] + bias);
        if (which == 0)
          qbuf[(((size_t)(bbb * NH + hh)) * SEQ + sr) * HD + dd] = hv;
        else if (which == 1)
          kbuf[(((size_t)(bbb * NH + hh)) * SEQ + sr) * HD + dd] = hv;
        else
          vt[(((size_t)(bbb * NH + hh)) * HD + dd) * SEQ + sr] = hv;
      }
  }
}

// ---------- 128x128 bf16 GEMM, B^T layout (C = A @ B^T), m97 structure ----------
// Used for the output projection (MODE 1 epilogue).
template<int MODE>
__global__ __launch_bounds__(256) void gemm_bt(
    const __hip_bfloat16* __restrict__ A, const __hip_bfloat16* __restrict__ B, int K,
    const float* __restrict__ bo, float* __restrict__ outp)
{
  __shared__ __hip_bfloat16 Abuf[2][128 * 32];
  __shared__ __hip_bfloat16 Bbuf[2][128 * 32];
  const int tid = threadIdx.x;
  const int l = tid & 63, w = tid >> 6;
  const int lr = l & 15, lg = l >> 4;
  const int wr = w >> 1, wc = w & 1;
  const int m0 = blockIdx.y * 128, n0 = blockIdx.x * 128;
  const int nK = K >> 5;

  f32x4 acc[4][4] = {};

  auto stage = [&](int buf, int kk) {
#pragma unroll
    for (int q2 = 0; q2 < 2; ++q2) {
      int flat = q2 * 256 + tid;
      int row = flat >> 2;
      int kb16 = (flat & 3) * 16;
      const __hip_bfloat16* ga = A + (size_t)(m0 + row) * K + kk + (kb16 >> 1);
      gload16(ga, &Abuf[buf][(q2 * 256 + w * 64) * 8]);
      const __hip_bfloat16* gb = B + (size_t)(n0 + row) * K + kk + (kb16 >> 1);
      gload16(gb, &Bbuf[buf][(q2 * 256 + w * 64) * 8]);
    }
  };

  stage(0, 0);
  for (int kt = 0; kt < nK; ++kt) {
    __syncthreads();
    if (kt + 1 < nK) stage((kt + 1) & 1, (kt + 1) * 32);
    const __hip_bfloat16* Ab = Abuf[kt & 1];
    const __hip_bfloat16* Bb = Bbuf[kt & 1];
    bf16x8 af[4], bfr[4];
#pragma unroll
    for (int fi = 0; fi < 4; ++fi)
      af[fi] = *reinterpret_cast<const bf16x8*>(&Ab[(wr * 64 + fi * 16 + lr) * 32 + lg * 8]);
#pragma unroll
    for (int fj = 0; fj < 4; ++fj)
      bfr[fj] = *reinterpret_cast<const bf16x8*>(&Bb[(wc * 64 + fj * 16 + lr) * 32 + lg * 8]);
#pragma unroll
    for (int fi = 0; fi < 4; ++fi)
#pragma unroll
      for (int fj = 0; fj < 4; ++fj)
        acc[fi][fj] = __builtin_amdgcn_mfma_f32_16x16x32_bf16(af[fi], bfr[fj], acc[fi][fj], 0, 0, 0);
  }

#pragma unroll
  for (int fj = 0; fj < 4; ++fj) {
    int ncol = n0 + wc * 64 + fj * 16 + lr;
    float bias = bo[ncol];
#pragma unroll
    for (int fi = 0; fi < 4; ++fi)
#pragma unroll
      for (int r = 0; r < 4; ++r) {
        int rowg = m0 + wr * 64 + fi * 16 + lg * 4 + r;
        outp[(size_t)rowg * DMODEL + ncol] = acc[fi][fj][r] + bias;
      }
  }
}

// ---------- RMSNorm (full-D) + 3D-grid RoPE, in-place on q,k ----------
// q additionally pre-scaled by 1/sqrt(HD) so attention skips the scale.
__global__ __launch_bounds__(256) void rmsrope_kernel(
    __hip_bfloat16* __restrict__ qb, __hip_bfloat16* __restrict__ kb,
    const float* __restrict__ gq, const float* __restrict__ gk,
    const float* __restrict__ fc, const float* __restrict__ fs,
    const int* __restrict__ gsz, const int* __restrict__ nmod)
{
  const int bs = blockIdx.x;
  const int b = bs / SEQ, s = bs - b * SEQ;
  const int t = threadIdx.x;
  const int f = gsz[0], h = gsz[1], wd = gsz[2];
  const int mm = nmod[0];
  const int seq_per = f * h * wd;
  int total_len = seq_per * mm; if (total_len > SEQ) total_len = SEQ;
  const bool dorope = s < total_len;
  int fi = 0, hi2 = 0, wi = 0;
  if (dorope) {
    int p = s % seq_per;
    fi = p / (h * wd);
    int rem = p - fi * (h * wd);
    hi2 = rem / wd;
    wi = rem - hi2 * wd;
  }
  float qv[3][2], kv[3][2];
  float sq = 0.f, sk = 0.f;
#pragma unroll
  for (int r = 0; r < 3; ++r) {
    int pi = t + r * 256;
    int head = pi >> 6;
    int dd = (pi & 63) * 2;
    size_t addr = (((size_t)(b * NH + head)) * SEQ + s) * HD + dd;
    __hip_bfloat162 q2 = *reinterpret_cast<const __hip_bfloat162*>(&qb[addr]);
    __hip_bfloat162 k2 = *reinterpret_cast<const __hip_bfloat162*>(&kb[addr]);
    qv[r][0] = __bfloat162float(q2.x); qv[r][1] = __bfloat162float(q2.y);
    kv[r][0] = __bfloat162float(k2.x); kv[r][1] = __bfloat162float(k2.y);
    sq += qv[r][0] * qv[r][0] + qv[r][1] * qv[r][1];
    sk += kv[r][0] * kv[r][0] + kv[r][1] * kv[r][1];
  }
#pragma unroll
  for (int off = 1; off < 64; off <<= 1) {
    sq += __shfl_xor(sq, off);
    sk += __shfl_xor(sk, off);
  }
  __shared__ float red[2][4];
  if ((t & 63) == 0) { red[0][t >> 6] = sq; red[1][t >> 6] = sk; }
  __syncthreads();
  float tq = red[0][0] + red[0][1] + red[0][2] + red[0][3];
  float tk = red[1][0] + red[1][1] + red[1][2] + red[1][3];
  float rq = rsqrtf(tq * (1.0f / DMODEL) + 1e-6f);
  float rk = rsqrtf(tk * (1.0f / DMODEL) + 1e-6f);
  const float scale = 0.08838834764831845f; // 1/sqrt(128), folded into q
#pragma unroll
  for (int r = 0; r < 3; ++r) {
    int pi = t + r * 256;
    int head = pi >> 6;
    int dd = (pi & 63) * 2;
    int col = pi * 2;
    size_t addr = (((size_t)(b * NH + head)) * SEQ + s) * HD + dd;
    float q0 = qv[r][0] * rq * gq[col], q1 = qv[r][1] * rq * gq[col + 1];
    float k0 = kv[r][0] * rk * gk[col], k1 = kv[r][1] * rk * gk[col + 1];
    if (dorope) {
      int j = pi & 63;
      int row = (j < 22) ? fi : (j < 43) ? hi2 : wi;
      float co = fc[row * 64 + j], si = fs[row * 64 + j];
      float a;
      a = q0 * co - q1 * si; q1 = q0 * si + q1 * co; q0 = a;
      a = k0 * co - k1 * si; k1 = k0 * si + k1 * co; k0 = a;
    }
    q0 *= scale; q1 *= scale;
    __hip_bfloat162 oq, ok;
    oq.x = __float2bfloat16(q0); oq.y = __float2bfloat16(q1);
    ok.x = __float2bfloat16(k0); ok.y = __float2bfloat16(k1);
    *reinterpret_cast<__hip_bfloat162*>(&qb[addr]) = oq;
    *reinterpret_cast<__hip_bfloat162*>(&kb[addr]) = ok;
  }
}

// ---------- flash attention v7: 4 waves x QBLK=32, 4-deep K ring, counted vmcnt ----------
// R6 structure + T3/T4: K staged 2 tiles ahead into a 4-buffer ring (race-free),
// vmcnt(4) counted waits (vmcnt(0) only at the tail), raw s_barrier.
__global__ __launch_bounds__(256, 2) void attn_kernel(
    const __hip_bfloat16* __restrict__ qb, const __hip_bfloat16* __restrict__ kbuf,
    const __hip_bfloat16* __restrict__ vt, const int* __restrict__ seq_lens,
    __hip_bfloat16* __restrict__ ob)
{
  const int orig = blockIdx.x;
  const int wg = (orig & 7) * 84 + (orig >> 3);
  const int bh = wg / 14, qt = wg % 14;
  const int bbb = bh / NH, hh = bh - bbb * NH;
  const int tid = threadIdx.x;
  const int w = tid >> 6, l = tid & 63;
  const int lq = l & 31, h = l >> 5;
  const int sl = seq_lens[bbb];
  const __hip_bfloat16* Q = qb + (size_t)bh * SEQ * HD;
  const char* Kc = (const char*)(kbuf + (size_t)bh * SEQ * HD);
  const __hip_bfloat16* Vp = vt + (size_t)bh * HD * SEQ;   // [128][1792]
  const int q0 = qt * 128 + w * 32;

  __shared__ __hip_bfloat16 Kt[4][64 * 128];   // 64 KB ring; byte ^= ((row&7)<<4)

  bf16x8 qf[8];
#pragma unroll
  for (int kc = 0; kc < 8; ++kc)
    qf[kc] = *reinterpret_cast<const bf16x8*>(
        &Q[(size_t)(q0 + lq) * HD + kc * 16 + h * 8]);

  f32x16 oacc[4] = {};                          // O[q_off][d0*32+lq]
  float m = -3e38f, ll = 0.f;                   // per-lane q-row softmax state

  const int nkt = (sl + 63) >> 6;

  auto stageK = [&](int t) {
    char* Lb = (char*)&Kt[t & 3][0];
    const int k0 = t * 64;
#pragma unroll
    for (int q2 = 0; q2 < 4; ++q2) {
      int chunk = q2 * 256 + tid;               // 16B chunk id in [0,1024)
      int row = chunk >> 4;                     // 16 chunks per 256B row
      int cb = (chunk & 15) << 4;
      int scb = cb ^ ((row & 7) << 4);          // inverse-swizzled source
      gload16(Kc + (size_t)(k0 + row) * 256 + scb, Lb + chunk * 16);
    }
  };

  stageK(0);
  if (nkt > 1) {
    stageK(1);
    asm volatile("s_waitcnt vmcnt(4)" ::: "memory");   // tile 0 landed
  } else {
    asm volatile("s_waitcnt vmcnt(0)" ::: "memory");
  }
  __builtin_amdgcn_s_barrier();

  for (int kt = 0; kt < nkt; ++kt) {
    __builtin_amdgcn_sched_barrier(0);
    const int k0 = kt * 64;
    if (kt + 2 < nkt) stageK(kt + 2);           // writes buf[(kt+2)&3] != cur, next
    const char* Kl = (const char*)&Kt[kt & 3][0];

    // swapped QK^T: S^T[k][q], 16 ds_read_b128 + 16 mfma_32x32x16
    f32x16 sa[2] = {};
#pragma unroll
    for (int cb = 0; cb < 2; ++cb) {
      int row = cb * 32 + lq;
      int swz = (row & 7) << 4;
#pragma unroll
      for (int kc = 0; kc < 8; ++kc) {
        bf16x8 kf = *reinterpret_cast<const bf16x8*>(
            Kl + row * 256 + ((kc * 32 + h * 16) ^ swz));
        sa[cb] = __builtin_amdgcn_mfma_f32_32x32x16_bf16(kf, qf[kc], sa[cb], 0, 0, 0);
      }
    }

    // mask tail (rare): k of sa[cb][r] = k0 + cb*32 + (r&3) + 8*(r>>2) + 4*h
    if (k0 + 64 > sl) {
#pragma unroll
      for (int cb = 0; cb < 2; ++cb)
#pragma unroll
        for (int r = 0; r < 16; ++r) {
          int kg = k0 + cb * 32 + (r & 3) + 8 * (r >> 2) + 4 * h;
          if (kg >= sl) sa[cb][r] = -3e38f;
        }
    }

    // in-register online softmax: lane owns q-row (lq), halves split across h
    float mx = -3e38f;
#pragma unroll
    for (int cb = 0; cb < 2; ++cb)
#pragma unroll
      for (int r = 0; r < 16; ++r) mx = fmaxf(mx, sa[cb][r]);
    mx = fmaxf(mx, __shfl_xor(mx, 32));

    if (__any(mx - m > 8.f)) {                  // defer-max (T13)
      float mn = fmaxf(m, mx);
      float alpha = __expf(m - mn);
      m = mn;
      ll *= alpha;
#pragma unroll
      for (int r = 0; r < 16; ++r) {
        float ar = __shfl(alpha, (r & 3) + 8 * (r >> 2) + 4 * h);
#pragma unroll
        for (int d0 = 0; d0 < 4; ++d0) oacc[d0][r] *= ar;
      }
    }

    float rs = 0.f;
#pragma unroll
    for (int cb = 0; cb < 2; ++cb)
#pragma unroll
      for (int r = 0; r < 16; ++r) {
        float e = __expf(sa[cb][r] - m);
        sa[cb][r] = e;
        rs += e;
      }
    rs += __shfl_xor(rs, 32);
    ll += rs;

    // P -> bf16 A-frags (pack + shfl_xor(32) exchange) and PV
#pragma unroll
    for (int c = 0; c < 4; ++c) {
      const int cb = c >> 1, r0 = 8 * (c & 1);
      unsigned A01 = pack2(sa[cb][r0],     sa[cb][r0 + 1]);
      unsigned A23 = pack2(sa[cb][r0 + 2], sa[cb][r0 + 3]);
      unsigned B01 = pack2(sa[cb][r0 + 4], sa[cb][r0 + 5]);
      unsigned B23 = pack2(sa[cb][r0 + 6], sa[cb][r0 + 7]);
      unsigned s1 = __shfl_xor(h ? A01 : B01, 32);
      unsigned s2 = __shfl_xor(h ? A23 : B23, 32);
      int4 wv;
      wv.x = (int)(h ? s1 : A01);
      wv.y = (int)(h ? s2 : A23);
      wv.z = (int)(h ? B01 : s1);
      wv.w = (int)(h ? B23 : s2);
      bf16x8 pa = *reinterpret_cast<bf16x8*>(&wv);
#pragma unroll
      for (int d0 = 0; d0 < 4; ++d0) {
        bf16x8 vv = *reinterpret_cast<const bf16x8*>(
            &Vp[(size_t)(d0 * 32 + lq) * SEQ + k0 + c * 16 + h * 8]);
        oacc[d0] = __builtin_amdgcn_mfma_f32_32x32x16_bf16(pa, vv, oacc[d0], 0, 0, 0);
      }
    }

    if (kt + 1 < nkt) {
      if (kt + 2 < nkt) asm volatile("s_waitcnt vmcnt(4)" ::: "memory");  // kt+1 landed
      else              asm volatile("s_waitcnt vmcnt(0)" ::: "memory");  // tail
      __builtin_amdgcn_s_barrier();
    }
  }

  // epilogue: normalize by per-q-row sum, write O
  float invl = 1.0f / ll;
#pragma unroll
  for (int r = 0; r < 16; ++r) {
    int qoff = (r & 3) + 8 * (r >> 2) + 4 * h;
    float ir = __shfl(invl, qoff);
    int qrow = q0 + qoff;
#pragma unroll
    for (int d0 = 0; d0 < 4; ++d0)
      ob[((size_t)bbb * SEQ + qrow) * DMODEL + hh * HD + d0 * 32 + lq] =
          __float2bfloat16(oacc[d0][r] * ir);
  }
}

// ---------- launch ----------
extern "C" void kernel_launch(void* const* d_in, const int* in_sizes, int n_in,
                              void* d_out, int out_size, void* d_ws, size_t ws_size,
                              hipStream_t stream) {
  const float* x   = (const float*)d_in[0];
  const int* seq_lens   = (const int*)d_in[1];
  const int* grid_sizes = (const int*)d_in[2];
  const float* fc  = (const float*)d_in[3];
  const float* fs  = (const float*)d_in[4];
  const float* Wq  = (const float*)d_in[5];
  const float* bq  = (const float*)d_in[6];
  const float* Wk  = (const float*)d_in[7];
  const float* bk  = (const float*)d_in[8];
  const float* Wv  = (const float*)d_in[9];
  const float* bv  = (const float*)d_in[10];
  const float* Wo  = (const float*)d_in[11];
  const float* bo  = (const float*)d_in[12];
  const float* gq  = (const float*)d_in[13];
  const float* gk  = (const float*)d_in[14];
  const int* nmod  = (const int*)d_in[15];
  float* out = (float*)d_out;

  char* ws = (char*)d_ws;
  __hip_bfloat16* xb   = (__hip_bfloat16*)(ws + 0);           // [7168][1536]
  __hip_bfloat16* wb   = (__hip_bfloat16*)(ws + 22020096);    // [4608][1536]
  __hip_bfloat16* wob  = (__hip_bfloat16*)(ws + 36175872);    // [1536][1536]
  __hip_bfloat16* qbuf = (__hip_bfloat16*)(ws + 40894464);    // [48][1792][128]
  __hip_bfloat16* kbuf = (__hip_bfloat16*)(ws + 62914560);    // [48][1792][128]
  __hip_bfloat16* vtb  = (__hip_bfloat16*)(ws + 84934656);    // [48][128][1792]
  __hip_bfloat16* ob   = xb;                                  // O reuses xb region

  cast_kernel<<<(11010048 / 4 + 255) / 256, 256, 0, stream>>>(x, xb, 11010048 / 4);
  cast_kernel<<<(2359296 / 4 + 255) / 256, 256, 0, stream>>>(Wq, wb, 2359296 / 4);
  cast_kernel<<<(2359296 / 4 + 255) / 256, 256, 0, stream>>>(Wk, wb + 2359296, 2359296 / 4);
  cast_kernel<<<(2359296 / 4 + 255) / 256, 256, 0, stream>>>(Wv, wb + 4718592, 2359296 / 4);
  cast_kernel<<<(2359296 / 4 + 255) / 256, 256, 0, stream>>>(Wo, wob, 2359296 / 4);

  gemm256_qkv<<<504, 512, 0, stream>>>(xb, wb, bq, bk, bv, qbuf, kbuf, vtb);
  rmsrope_kernel<<<7168, 256, 0, stream>>>(qbuf, kbuf, gq, gk, fc, fs, grid_sizes, nmod);
  attn_kernel<<<672, 256, 0, stream>>>(qbuf, kbuf, vtb, seq_lens, ob);
  gemm_bt<1><<<dim3(12, 56), 256, 0, stream>>>(ob, wob, 1536, bo, out);
}